// Round 7
// baseline (1120.181 us; speedup 1.0000x reference)
//
#include <hip/hip_runtime.h>

#define BB 256
#define LL 1024
#define TT 128
#define NTH 512    // 8 waves = 2 waves/SIMD (best measured)
#define NG 8       // pred groups; wave g owns preds [16g, 16g+16)
#define PS 132     // pv/pi stride (pad: 132 % 32 = 4)

// LDS-only barrier: does NOT drain vmcnt, so in-flight global prefetch loads
// stay outstanding across the barrier (__syncthreads drains vmcnt(0) too).
__device__ __forceinline__ void lds_barrier() {
    asm volatile("s_waitcnt lgkmcnt(0)\n\ts_barrier" ::);
}

struct SmallSmem {
    float state[TT];          // current Viterbi state (float4-aligned, first)
    float pv[NG * PS];        // pv[g*PS + j]: group-g partial best value, col j
    int   pi[NG * PS];        // pi[g*PS + j]: matching GLOBAL pred index
    unsigned char tags[LL];   // decoded tags staging
};

__global__ __launch_bounds__(NTH)
void viterbi_kernel(const float* __restrict__ x,
                    const int* __restrict__ lengths,
                    const float* __restrict__ trans,
                    int* __restrict__ out) {
    __shared__ SmallSmem sm;
    extern __shared__ unsigned char bp[];   // LL*TT bytes, backpointers in LDS

    const int b    = blockIdx.x;
    const int tid  = threadIdx.x;
    const int lane = tid & 63;
    const int g    = tid >> 6;        // wave index = pred group
    const int j1   = lane;            // column A
    const int j2   = lane + 64;       // column B

    int lenb = lengths[b];
    if (lenb < 1) lenb = 1;
    if (lenb > LL) lenb = LL;

    // Register-cache trans for 16 preds x 2 columns.
    float tc1[16], tc2[16];
    #pragma unroll
    for (int ii = 0; ii < 16; ++ii) {
        tc1[ii] = trans[(g * 16 + ii) * TT + j1];
        tc2[ii] = trans[(g * 16 + ii) * TT + j2];
    }

    const float* xb = x + (size_t)b * LL * TT;

    if (tid < TT) sm.state[tid] = xb[tid];

    // Emission prefetch for phase-2 owners (tid<128 own column tid).
    float xv_cur = 0.0f, xv_next = 0.0f;
    if (tid < TT && lenb > 1) xv_cur = xb[TT + tid];
    lds_barrier();

    // ---------------- forward ----------------
    for (int t = 1; t < lenb; ++t) {
        if (tid < TT) {   // wave-uniform guard; load floats across lgkm barriers
            int tn = (t + 1 < lenb) ? (t + 1) : (lenb - 1);
            xv_next = xb[tn * TT + tid];
        }

        // Phase 1: 16 preds (this wave's slice) x 2 columns.
        // Residue accumulator r tracks local ii = 4k+r, k ascending; strict >
        // keeps the LOWEST index per residue (jnp.argmax = first max).
        const float4* st4 = reinterpret_cast<const float4*>(sm.state + g * 16);
        float a0 = -3.4e38f, a1 = -3.4e38f, a2 = -3.4e38f, a3 = -3.4e38f;
        float c0 = -3.4e38f, c1 = -3.4e38f, c2 = -3.4e38f, c3 = -3.4e38f;
        int   ai0 = 0, ai1 = 1, ai2 = 2, ai3 = 3;
        int   ci0 = 0, ci1 = 1, ci2 = 2, ci3 = 3;
        #pragma unroll
        for (int k = 0; k < 4; ++k) {
            float4 sv = st4[k];            // wave-uniform broadcast ds_read_b128
            float sA0 = sv.x + tc1[4 * k + 0], sB0 = sv.x + tc2[4 * k + 0];
            float sA1 = sv.y + tc1[4 * k + 1], sB1 = sv.y + tc2[4 * k + 1];
            float sA2 = sv.z + tc1[4 * k + 2], sB2 = sv.z + tc2[4 * k + 2];
            float sA3 = sv.w + tc1[4 * k + 3], sB3 = sv.w + tc2[4 * k + 3];
            if (sA0 > a0) { a0 = sA0; ai0 = 4 * k + 0; }
            if (sA1 > a1) { a1 = sA1; ai1 = 4 * k + 1; }
            if (sA2 > a2) { a2 = sA2; ai2 = 4 * k + 2; }
            if (sA3 > a3) { a3 = sA3; ai3 = 4 * k + 3; }
            if (sB0 > c0) { c0 = sB0; ci0 = 4 * k + 0; }
            if (sB1 > c1) { c1 = sB1; ci1 = 4 * k + 1; }
            if (sB2 > c2) { c2 = sB2; ci2 = 4 * k + 2; }
            if (sB3 > c3) { c3 = sB3; ci3 = 4 * k + 3; }
        }
        // Merge residues with EXACT first-index tie-break (local index order).
        float av = a0; int ax = ai0;
        if (a1 > av || (a1 == av && ai1 < ax)) { av = a1; ax = ai1; }
        if (a2 > av || (a2 == av && ai2 < ax)) { av = a2; ax = ai2; }
        if (a3 > av || (a3 == av && ai3 < ax)) { av = a3; ax = ai3; }
        float cv = c0; int cx = ci0;
        if (c1 > cv || (c1 == cv && ci1 < cx)) { cv = c1; cx = ci1; }
        if (c2 > cv || (c2 == cv && ci2 < cx)) { cv = c2; cx = ci2; }
        if (c3 > cv || (c3 == cv && ci3 < cx)) { cv = c3; cx = ci3; }
        // Lane-consecutive writes -> conflict-free.
        sm.pv[g * PS + j1] = av;  sm.pi[g * PS + j1] = ax + g * 16;
        sm.pv[g * PS + j2] = cv;  sm.pi[g * PS + j2] = cx + g * 16;
        lds_barrier();

        // Phase 2 (waves 0-1): merge 8 group partials for column j = tid.
        // Groups ascend in pred index; strict > (earlier group wins ties)
        // = exact first-index semantics.
        if (tid < TT) {
            float mv = sm.pv[tid];
            int   mx = sm.pi[tid];
            #pragma unroll
            for (int gg = 1; gg < NG; ++gg) {
                float v = sm.pv[gg * PS + tid];
                int   i = sm.pi[gg * PS + tid];
                if (v > mv) { mv = v; mx = i; }
            }
            sm.state[tid] = mv + xv_cur;
            bp[t * TT + tid] = (unsigned char)mx;
            xv_cur = xv_next;
        }
        lds_barrier();
    }

    // ---------------- backward ----------------
    if (tid == 0) {
        // last_tag = argmax(state), first-index tiebreak (sequential strict >)
        float bv = sm.state[0]; int ix = 0;
        for (int i = 1; i < TT; ++i) {
            float v = sm.state[i];
            if (v > bv) { bv = v; ix = i; }
        }
        int carry = ix;
        for (int t = lenb - 1; t >= 1; --t) {
            sm.tags[t] = (unsigned char)carry;
            carry = bp[t * TT + carry];
        }
        sm.tags[0] = (unsigned char)carry;
    }
    lds_barrier();

    int* outb = out + (size_t)b * LL;
    for (int t = tid; t < LL; t += NTH)
        outb[t] = (t < lenb) ? (int)sm.tags[t] : 0;
}

extern "C" void kernel_launch(void* const* d_in, const int* in_sizes, int n_in,
                              void* d_out, int out_size, void* d_ws, size_t ws_size,
                              hipStream_t stream) {
    const float* x       = (const float*)d_in[0];
    const int*   lengths = (const int*)d_in[1];
    // d_in[2] = tags (unused by decode)
    const float* trans   = (const float*)d_in[3];
    int*         out     = (int*)d_out;

    // Backpointers entirely in LDS: 128 KB dynamic + ~10 KB static < 160 KB.
    const int dyn = LL * TT;  // 131072 bytes
    hipFuncSetAttribute((const void*)&viterbi_kernel,
                        hipFuncAttributeMaxDynamicSharedMemorySize, dyn);
    viterbi_kernel<<<BB, NTH, dyn, stream>>>(x, lengths, trans, out);
}

// Round 8
// 948.532 us; speedup vs baseline: 1.1810x; 1.1810x over previous
//
#include <hip/hip_runtime.h>

#define BB 256
#define LL 1024
#define TT 128
#define NTH 512    // 8 waves = 2 waves/SIMD (best measured)

// LDS-only barrier: does NOT drain vmcnt, so in-flight global prefetch loads
// stay outstanding across the barrier (__syncthreads drains vmcnt(0) too).
__device__ __forceinline__ void lds_barrier() {
    asm volatile("s_waitcnt lgkmcnt(0)\n\ts_barrier" ::);
}

struct SmallSmem {
    float state[TT];          // current Viterbi state (16B-aligned, first)
    float pv4[TT * 4];        // pv4[j*4+q]: quarter-q partial best value, col j
    int   pi4[TT * 4];        // pi4[j*4+q]: matching GLOBAL pred index
    unsigned char tags[LL];   // decoded tags staging
};

__global__ __launch_bounds__(NTH)
void viterbi_kernel(const float* __restrict__ x,
                    const int* __restrict__ lengths,
                    const float* __restrict__ trans,
                    int* __restrict__ out) {
    __shared__ SmallSmem sm;
    extern __shared__ unsigned char bp[];   // LL*TT bytes, backpointers in LDS

    const int b   = blockIdx.x;
    const int tid = threadIdx.x;
    const int j   = tid & (TT - 1);   // tag column 0..127
    const int q   = tid >> 7;         // predecessor quarter: i in [32q, 32q+32)

    int lenb = lengths[b];
    if (lenb < 1) lenb = 1;
    if (lenb > LL) lenb = LL;

    // Register-cache this thread's 32 trans values: tc[ii] = trans[32q+ii][j]
    float tc[32];
    #pragma unroll
    for (int ii = 0; ii < 32; ++ii)
        tc[ii] = trans[(q * 32 + ii) * TT + j];

    const float* xb = x + (size_t)b * LL * TT;

    if (tid < TT) sm.state[tid] = xb[tid];

    // Emission prefetch, depth 2: xv0 = x[t][j] when step t runs; loads have
    // ~2 step-times (>> HBM latency) to land before consumption.
    float xv0 = 0.0f, xv1 = 0.0f, xv2 = 0.0f;
    if (tid < TT && lenb > 1) {
        xv0 = xb[TT + j];                              // t = 1
        int t2 = (2 < lenb) ? 2 : (lenb - 1);
        xv1 = xb[t2 * TT + j];                         // t = 2 (clamped)
    }
    lds_barrier();

    // ---------------- forward ----------------
    for (int t = 1; t < lenb; ++t) {
        if (tid < TT) {   // issue load for step t+2 (floats across lgkm barriers)
            int tn = (t + 2 < lenb) ? (t + 2) : (lenb - 1);
            xv2 = xb[tn * TT + j];
        }

        // Phase 1: scan 32 predecessors: score = state[i] + trans[i][j].
        // Residue accumulator r tracks local ii = 4k+r, k ascending; strict >
        // keeps the LOWEST index within each residue (jnp.argmax = first max).
        float best0 = -3.4e38f, best1 = -3.4e38f, best2 = -3.4e38f, best3 = -3.4e38f;
        int   bi0 = 0, bi1 = 1, bi2 = 2, bi3 = 3;
        const float4* st4 = reinterpret_cast<const float4*>(sm.state + q * 32);
        #pragma unroll
        for (int k = 0; k < 8; ++k) {
            float4 sv = st4[k];            // wave-uniform broadcast ds_read_b128
            float s0 = sv.x + tc[4 * k + 0];
            float s1 = sv.y + tc[4 * k + 1];
            float s2 = sv.z + tc[4 * k + 2];
            float s3 = sv.w + tc[4 * k + 3];
            if (s0 > best0) { best0 = s0; bi0 = 4 * k + 0; }
            if (s1 > best1) { best1 = s1; bi1 = 4 * k + 1; }
            if (s2 > best2) { best2 = s2; bi2 = 4 * k + 2; }
            if (s3 > best3) { best3 = s3; bi3 = 4 * k + 3; }
        }
        // Merge residues with EXACT first-index tie-break (local index order).
        float bb = best0; int bi = bi0;
        if (best1 > bb || (best1 == bb && bi1 < bi)) { bb = best1; bi = bi1; }
        if (best2 > bb || (best2 == bb && bi2 < bi)) { bb = best2; bi = bi2; }
        if (best3 > bb || (best3 == bb && bi3 < bi)) { bb = best3; bi = bi3; }
        // Transposed partials: column-major-by-j so phase 2 reads b128.
        // (8-way bank conflict on this write: ~6 cyc, negligible per m136.)
        sm.pv4[j * 4 + q] = bb;
        sm.pi4[j * 4 + q] = bi + q * 32;   // global predecessor index
        lds_barrier();

        // Phase 2 (threads 0..127): merge the 4 quarter-partials for col tid.
        // One b128 for values + one for indices (lane-consecutive, no conflict).
        // Quarters ascend in pred index; strict > (earlier quarter wins ties)
        // = exact first-index semantics.
        if (tid < TT) {
            float4 pv = *reinterpret_cast<const float4*>(&sm.pv4[tid * 4]);
            int4   pi = *reinterpret_cast<const int4*>(&sm.pi4[tid * 4]);
            float mv = pv.x; int mx = pi.x;
            if (pv.y > mv) { mv = pv.y; mx = pi.y; }
            if (pv.z > mv) { mv = pv.z; mx = pi.z; }
            if (pv.w > mv) { mv = pv.w; mx = pi.w; }
            sm.state[tid] = mv + xv0;
            bp[t * TT + tid] = (unsigned char)mx;
            xv0 = xv1; xv1 = xv2;   // rotate prefetch pipeline
        }
        lds_barrier();
    }

    // ---------------- backward ----------------
    if (tid == 0) {
        // last_tag = argmax(state), first-index tiebreak (sequential strict >)
        float bv = sm.state[0]; int ix = 0;
        for (int i = 1; i < TT; ++i) {
            float v = sm.state[i];
            if (v > bv) { bv = v; ix = i; }
        }
        int carry = ix;
        for (int t = lenb - 1; t >= 1; --t) {
            sm.tags[t] = (unsigned char)carry;
            carry = bp[t * TT + carry];
        }
        sm.tags[0] = (unsigned char)carry;
    }
    lds_barrier();

    int* outb = out + (size_t)b * LL;
    for (int t = tid; t < LL; t += NTH)
        outb[t] = (t < lenb) ? (int)sm.tags[t] : 0;
}

extern "C" void kernel_launch(void* const* d_in, const int* in_sizes, int n_in,
                              void* d_out, int out_size, void* d_ws, size_t ws_size,
                              hipStream_t stream) {
    const float* x       = (const float*)d_in[0];
    const int*   lengths = (const int*)d_in[1];
    // d_in[2] = tags (unused by decode)
    const float* trans   = (const float*)d_in[3];
    int*         out     = (int*)d_out;

    // Backpointers entirely in LDS: 128 KB dynamic + ~5.6 KB static < 160 KB.
    const int dyn = LL * TT;  // 131072 bytes
    hipFuncSetAttribute((const void*)&viterbi_kernel,
                        hipFuncAttributeMaxDynamicSharedMemorySize, dyn);
    viterbi_kernel<<<BB, NTH, dyn, stream>>>(x, lengths, trans, out);
}